// Round 7
// baseline (319.554 us; speedup 1.0000x reference)
//
#include <hip/hip_runtime.h>
#include <hip/hip_bf16.h>

#define BB 4
#define NN 1369
#define DIMM 1024
#define VDIMM 1536
#define HH 16
#define MM (BB*NN)      // 5476
#define MPAD 5504       // 43*128 = 86*64
#define NPAD 1408       // 22*64
#define KVB 64
#define NT (NPAD/KVB)   // 22
#define QSCALE 0.18028334f   // 0.125 * log2(e)

typedef __attribute__((ext_vector_type(4))) float f32x4;
typedef __attribute__((ext_vector_type(8))) __bf16 bf16x8;
typedef __attribute__((ext_vector_type(4))) __bf16 bf16x4;

#define GLOAD_LDS(gsrc, ldst) \
  __builtin_amdgcn_global_load_lds((const __attribute__((address_space(1))) unsigned int*)(gsrc), \
                                   (__attribute__((address_space(3))) unsigned int*)(ldst), 16, 0, 0)

// ---------------- fused input converts: x then val ----------------
__global__ __launch_bounds__(256) void cvt_inputs(const float* __restrict__ x,
                                                  const float* __restrict__ val,
                                                  __bf16* __restrict__ xb,
                                                  __bf16* __restrict__ vb) {
  const int NX = MM * 1024 / 4;          // 1401856
  const int NV = MM * 1536 / 4;          // 2102784
  int i = blockIdx.x * blockDim.x + threadIdx.x;
  int st = gridDim.x * blockDim.x;
  for (; i < NX + NV; i += st) {
    const float* s; __bf16* d; int j;
    if (i < NX) { s = x; d = xb; j = i; }
    else        { s = val; d = vb; j = i - NX; }
    f32x4 v = ((const f32x4*)s)[j];
    bf16x4 o;
    o[0] = (__bf16)v[0]; o[1] = (__bf16)v[1];
    o[2] = (__bf16)v[2]; o[3] = (__bf16)v[3];
    ((bf16x4*)d)[j] = o;
  }
}

// ---------------- fused weight converts: wq, wk, wv, wp ----------------
__global__ __launch_bounds__(256) void cvt_weights(
    const float* __restrict__ wq, const float* __restrict__ wk,
    const float* __restrict__ wv, const float* __restrict__ wp,
    __bf16* __restrict__ wqb, __bf16* __restrict__ wkvb, __bf16* __restrict__ wpb) {
  const int NQ = 1024 * 1024 / 4;        // 262144
  const int NK = 1024 * 1536 / 4;        // 393216
  int i = blockIdx.x * blockDim.x + threadIdx.x;
  int st = gridDim.x * blockDim.x;
  for (; i < 2 * NQ + 2 * NK; i += st) {
    const float* s; __bf16* d; int j = i;
    if (j < NQ) { s = wq; d = wqb; }
    else if (j < NQ + NK) { j -= NQ; s = wk; d = wkvb; }
    else if (j < NQ + 2 * NK) { j -= NQ + NK; s = wv; d = wkvb + (size_t)1024 * 1536; }
    else { j -= NQ + 2 * NK; s = wp; d = wpb; }
    f32x4 v = ((const f32x4*)s)[j];
    bf16x4 o;
    o[0] = (__bf16)v[0]; o[1] = (__bf16)v[1];
    o[2] = (__bf16)v[2]; o[3] = (__bf16)v[3];
    ((bf16x4*)d)[j] = o;
  }
}

// ---------------- RoPE tables [1369][64] ----------------
__global__ __launch_bounds__(256) void rope_tables(float* __restrict__ cosT,
                                                   float* __restrict__ sinT) {
  int idx = blockIdx.x * blockDim.x + threadIdx.x;
  if (idx >= NN * 64) return;
  int n = idx >> 6, d = idx & 63;
  int r = n / 37, c = n % 37;
  int m = (d < 32) ? (d >> 1) : ((d - 32) >> 1);
  float p = (d < 32) ? (float)r : (float)c;
  float inv = powf(10000.f, -(float)m * (1.f / 16.f));
  float a = p * inv;
  cosT[idx] = cosf(a);
  sinT[idx] = sinf(a);
}

// ---------------- mask: detect dtype, canonicalize to ADDITIVE float [4][NPAD] ----------------
__global__ __launch_bounds__(256) void mask_prep(const void* __restrict__ mask,
                                                 float* __restrict__ maskA) {
  __shared__ int flags[2];
  int t = threadIdx.x;
  if (t < 2) flags[t] = 0;
  __syncthreads();
  const unsigned int* mw = (const unsigned int*)mask;
  for (int i = t; i < NN; i += blockDim.x) {
    unsigned int w = mw[i];
    if (w == 0x3F800000u) atomicOr(&flags[1], 1);
    else if (w > 1u) atomicOr(&flags[0], 1);
  }
  __syncthreads();
  int md = flags[1] ? 2 : (flags[0] ? 1 : 0);  // 0=int32, 1=bool bytes, 2=float32
  const unsigned char* mb = (const unsigned char*)mask;
  const float* mf = (const float*)mask;
  for (int i = t; i < BB * NPAD; i += blockDim.x) {
    int b = i / NPAD, key = i % NPAD;
    float v = -1e30f;
    if (key < NN) {
      int idx = b * NN + key;
      bool on = (md == 0) ? (mw[idx] != 0u) : (md == 1) ? (mb[idx] != 0) : (mf[idx] != 0.f);
      if (on) v = 0.f;
    }
    maskA[i] = v;
  }
}

// ---------------- merged Q + KV projection GEMM ----------------
// 2064 blocks (8.1/CU): orig%3==0 -> Q block (688), else KV block (1376).
// All tiles 128x64, 4 waves stacked in M (wave 32x64), 2-phase dbuf LDS,
// fragment-ordered layout (conflict-free), XCD-swizzled flat grid.
__global__ __launch_bounds__(256) void gemm_qkv(
    const __bf16* __restrict__ xb, const __bf16* __restrict__ wqb,
    const __bf16* __restrict__ vb, const __bf16* __restrict__ wkvb,
    __bf16* __restrict__ Qb, __bf16* __restrict__ Kb, __bf16* __restrict__ Vtb,
    const float* __restrict__ cosT, const float* __restrict__ sinT) {
  __shared__ __bf16 As[2][128 * 32];
  __shared__ __bf16 Bs[2][64 * 32];
  const int tid = threadIdx.x;
  const int w = tid >> 6, l = tid & 63;
  const int i0 = blockIdx.x;
  const int orig = (i0 & 7) * 258 + (i0 >> 3);   // 2064 = 8*258, bijective
  const int third = orig / 3, rem = orig - third * 3;
  const bool isQ = (rem == 0);
  int tN, tM, K;
  const __bf16 *A, *W;
  if (isQ) {
    const int qid = third;              // [0,688)
    tN = qid & 15; tM = qid >> 4; K = 1024; A = xb; W = wqb;
  } else {
    const int kvid = third * 2 + (rem - 1);   // [0,1376) bijective
    tN = kvid & 31; tM = kvid >> 5; K = 1536; A = vb; W = wkvb;
  }
  const int wmo = w * 32;
  const int lo = l & 15, hi = l >> 4;

  const __bf16* Asrc = A + (size_t)(tM * 128 + lo) * K + hi * 8;
  const __bf16* Wsrc = W + (size_t)(tN * 64 + lo) * K + hi * 8;

  f32x4 zero = {0.f, 0.f, 0.f, 0.f};
  f32x4 acc[2][4];
#pragma unroll
  for (int i = 0; i < 2; ++i)
#pragma unroll
    for (int j = 0; j < 4; ++j) acc[i][j] = zero;

  auto GSTAGE = [&](int buf, int k0) {
#pragma unroll
    for (int j = 0; j < 2; ++j) {
      const int c = j * 4 + w;
      GLOAD_LDS(Asrc + (size_t)c * 16 * K + k0, (char*)&As[buf][c * 512]);
    }
    GLOAD_LDS(Wsrc + (size_t)w * 16 * K + k0, (char*)&Bs[buf][w * 512]);
  };

  const int nk = K >> 5;
  GSTAGE(0, 0);
  int cur = 0;
  const int ga = w * 2;
  for (int t = 0; t < nk; ++t) {
    __syncthreads();                        // buf[cur] staged (all waves)
    if (t + 1 < nk) GSTAGE(cur ^ 1, (t + 1) * 32);
    bf16x8 af[2], bfr[4];
#pragma unroll
    for (int mi = 0; mi < 2; ++mi)
      af[mi] = *(const bf16x8*)&As[cur][(ga + mi) * 512 + hi * 128 + lo * 8];
#pragma unroll
    for (int ni = 0; ni < 4; ++ni)
      bfr[ni] = *(const bf16x8*)&Bs[cur][ni * 512 + hi * 128 + lo * 8];
    __builtin_amdgcn_s_setprio(1);
#pragma unroll
    for (int mi = 0; mi < 2; ++mi)
#pragma unroll
      for (int ni = 0; ni < 4; ++ni)
        acc[mi][ni] = __builtin_amdgcn_mfma_f32_16x16x32_bf16(af[mi], bfr[ni], acc[mi][ni], 0, 0, 0);
    __builtin_amdgcn_s_setprio(0);
    cur ^= 1;
  }

  const int m_base = tM * 128 + wmo;
  const bool isV = !isQ && (tN >= 16);     // block-uniform
#pragma unroll
  for (int mi = 0; mi < 2; ++mi) {
    const int m4 = m_base + mi * 16 + hi * 4;
    if (isV) {
      if (m4 < MM) {
        const int b0 = m4 / NN, n0 = m4 % NN;
#pragma unroll
        for (int ni = 0; ni < 4; ++ni) {
          const int o2 = tN * 64 + ni * 16 + lo - 1024;
          const int h = o2 >> 6, d = o2 & 63;
          if (n0 <= NN - 4) {
            bf16x4 pv;
#pragma unroll
            for (int r = 0; r < 4; ++r) pv[r] = (__bf16)acc[mi][ni][r];
            *(bf16x4*)&Vtb[((size_t)(b0 * HH + h) * 64 + d) * NPAD + n0] = pv;
          } else {
#pragma unroll
            for (int r = 0; r < 4; ++r) {
              const int mr = m4 + r;
              const int br = mr / NN, nr = mr % NN;
              Vtb[((size_t)(br * HH + h) * 64 + d) * NPAD + nr] = (__bf16)acc[mi][ni][r];
            }
          }
        }
      }
    } else {
#pragma unroll
      for (int r = 0; r < 4; ++r) {
        const int mrow = m4 + r;
#pragma unroll
        for (int ni = 0; ni < 4; ++ni) {
          const int col = tN * 64 + ni * 16 + lo;
          float v = acc[mi][ni][r];
          float pprt = __shfl_xor(v, 1);   // RoPE partner (d^1), same mrow
          if (mrow < MM) {
            int b = mrow / NN, n = mrow % NN;
            int h = col >> 6, d = col & 63;
            float cs = cosT[n * 64 + d], sn = sinT[n * 64 + d];
            float out = v * cs + (((d & 1) == 0) ? -pprt : pprt) * sn;
            if (isQ) {
              out *= QSCALE;
              Qb[((size_t)(b * HH + h) * NPAD + n) * 64 + d] = (__bf16)out;
            } else {
              Kb[((size_t)(b * HH + h) * NPAD + n) * 64 + d] = (__bf16)out;
            }
          }
        }
      }
    }
  }
}

// ---------------- output projection: 64x64 tiles, 128-thread blocks ----------------
// 1376 blocks (5.4/CU), 2 waves of 32x64, 2-phase dbuf, fragment-ordered LDS.
__global__ __launch_bounds__(128) void gemm_out(
    const __bf16* __restrict__ A, const __bf16* __restrict__ W,
    float* __restrict__ of32, const float* __restrict__ bp) {
  __shared__ __bf16 As[2][64 * 32];
  __shared__ __bf16 Bs[2][64 * 32];
  const int tid = threadIdx.x;
  const int w = tid >> 6, l = tid & 63;
  const int i0 = blockIdx.x;
  const int orig = (i0 & 7) * 172 + (i0 >> 3);   // 1376 = 8*172
  const int tN = orig & 15, tM = orig >> 4;      // tM in [0,86)
  const int K = 1024;
  const int lo = l & 15, hi = l >> 4;

  const __bf16* Asrc = A + (size_t)(tM * 64 + lo) * K + hi * 8;
  const __bf16* Wsrc = W + (size_t)(tN * 64 + lo) * K + hi * 8;

  f32x4 zero = {0.f, 0.f, 0.f, 0.f};
  f32x4 acc[2][4];
#pragma unroll
  for (int i = 0; i < 2; ++i)
#pragma unroll
    for (int j = 0; j < 4; ++j) acc[i][j] = zero;

  auto GSTAGE = [&](int buf, int k0) {
#pragma unroll
    for (int j = 0; j < 2; ++j) {
      const int c = j * 2 + w;
      GLOAD_LDS(Asrc + (size_t)c * 16 * K + k0, (char*)&As[buf][c * 512]);
      GLOAD_LDS(Wsrc + (size_t)c * 16 * K + k0, (char*)&Bs[buf][c * 512]);
    }
  };

  GSTAGE(0, 0);
  int cur = 0;
  const int ga = w * 2;
  for (int t = 0; t < 32; ++t) {
    __syncthreads();
    if (t + 1 < 32) GSTAGE(cur ^ 1, (t + 1) * 32);
    bf16x8 af[2], bfr[4];
#pragma unroll
    for (int mi = 0; mi < 2; ++mi)
      af[mi] = *(const bf16x8*)&As[cur][(ga + mi) * 512 + hi * 128 + lo * 8];
#pragma unroll
    for (int ni = 0; ni < 4; ++ni)
      bfr[ni] = *(const bf16x8*)&Bs[cur][ni * 512 + hi * 128 + lo * 8];
    __builtin_amdgcn_s_setprio(1);
#pragma unroll
    for (int mi = 0; mi < 2; ++mi)
#pragma unroll
      for (int ni = 0; ni < 4; ++ni)
        acc[mi][ni] = __builtin_amdgcn_mfma_f32_16x16x32_bf16(af[mi], bfr[ni], acc[mi][ni], 0, 0, 0);
    __builtin_amdgcn_s_setprio(0);
    cur ^= 1;
  }

  const int m_base = tM * 64 + w * 32;
#pragma unroll
  for (int mi = 0; mi < 2; ++mi) {
#pragma unroll
    for (int r = 0; r < 4; ++r) {
      const int mrow = m_base + mi * 16 + hi * 4 + r;
      if (mrow < MM) {
#pragma unroll
        for (int ni = 0; ni < 4; ++ni) {
          const int col = tN * 64 + ni * 16 + lo;
          of32[(size_t)mrow * DIMM + col] = acc[mi][ni][r] + bp[col];
        }
      }
    }
  }
}

__device__ inline unsigned int pk2(float a, float b) {
  unsigned int ua = (unsigned int)__builtin_bit_cast(unsigned short, (__bf16)a);
  unsigned int ub = (unsigned int)__builtin_bit_cast(unsigned short, (__bf16)b);
  return ua | (ub << 16);
}

// ---------------- flash attention (unchanged from R5) ----------------
__global__ __launch_bounds__(256) void attn_kernel(
    const __bf16* __restrict__ Qb, const __bf16* __restrict__ Kb,
    const __bf16* __restrict__ Vtb, const float* __restrict__ maskA,
    float* __restrict__ AO) {
  __shared__ __bf16 Ks[2][64 * 64];
  __shared__ __bf16 Vs[2][64 * 64];
  __shared__ unsigned int Plds[4][16 * 32];
  const int tid = threadIdx.x;
  const int w = tid >> 6, l = tid & 63;
  const int lo = l & 15, hi = l >> 4;

  const int i = blockIdx.x;
  const int orig = (i & 7) * 176 + (i >> 3);
  const int bh = orig / NT;
  const int qt = orig % NT;
  const int b = bh >> 4;
  const int q0 = qt * 64 + w * 16;

  const __bf16* Qp = Qb + ((size_t)bh * NPAD + q0) * 64;
  bf16x8 qf0 = *(const bf16x8*)&Qp[lo * 64 + hi * 8];
  bf16x8 qf1 = *(const bf16x8*)&Qp[lo * 64 + 32 + hi * 8];

  const int row8 = l >> 3;
  const int swz16 = ((l & 7) ^ row8) << 4;
  const int lo7 = lo & 7;
  const int swzW = (lo & 7) << 2;

  f32x4 zero = {0.f, 0.f, 0.f, 0.f};
  f32x4 O[4];
#pragma unroll
  for (int n = 0; n < 4; ++n) O[n] = zero;
  float lr = 0.f;
  const float* mk = maskA + b * NPAD;

#define STAGE(buf, k0)                                                                   \
  {                                                                                      \
    _Pragma("unroll") for (int j = 0; j < 2; ++j) {                                      \
      const int rbase = (j * 4 + w) * 8;                                                 \
      const char* ksrc = (const char*)Kb +                                               \
          ((size_t)bh * NPAD + (k0) + rbase + row8) * 128 + swz16;                       \
      GLOAD_LDS(ksrc, (char*)&Ks[buf][0] + rbase * 128);                                 \
      const char* vsrc = (const char*)Vtb +                                              \
          ((size_t)(bh * 64 + rbase + row8) * NPAD + (k0)) * 2 + swz16;                  \
      GLOAD_LDS(vsrc, (char*)&Vs[buf][0] + rbase * 128);                                 \
    }                                                                                    \
  }

  STAGE(0, 0);
  __syncthreads();
  int cur = 0;

  for (int t = 0; t < NT; ++t) {
    if (t + 1 < NT) STAGE(cur ^ 1, (t + 1) * KVB);

    const __bf16* KB = &Ks[cur][0];
    const __bf16* VB = &Vs[cur][0];

    f32x4 mv[4];
#pragma unroll
    for (int c = 0; c < 4; ++c) mv[c] = *(const f32x4*)&mk[t * KVB + c * 16 + hi * 4];

    f32x4 S[4];
    __builtin_amdgcn_s_setprio(1);
#pragma unroll
    for (int c = 0; c < 4; ++c) {
      const int kr = c * 16 + lo;
      bf16x8 kfa = *(const bf16x8*)&KB[kr * 64 + ((hi ^ lo7) * 8)];
      bf16x8 kfb = *(const bf16x8*)&KB[kr * 64 + (((hi + 4) ^ lo7) * 8)];
      f32x4 s = __builtin_amdgcn_mfma_f32_16x16x32_bf16(kfa, qf0, zero, 0, 0, 0);
      S[c]     = __builtin_amdgcn_mfma_f32_16x16x32_bf16(kfb, qf1, s, 0, 0, 0);
    }
    __builtin_amdgcn_s_setprio(0);

    float rs = 0.f;
#pragma unroll
    for (int c = 0; c < 4; ++c) {
      float p0 = exp2f(S[c][0] + mv[c][0]);
      float p1 = exp2f(S[c][1] + mv[c][1]);
      float p2 = exp2f(S[c][2] + mv[c][2]);
      float p3 = exp2f(S[c][3] + mv[c][3]);
      rs += (p0 + p1) + (p2 + p3);
      uint2 pw = {pk2(p0, p1), pk2(p2, p3)};
      *(uint2*)&Plds[w][lo * 32 + ((8 * c + 2 * hi) ^ swzW)] = pw;
    }
    lr += rs;

    bf16x8 pf0 = *(const bf16x8*)&Plds[w][lo * 32 + ((4 * hi) ^ swzW)];
    bf16x8 pf1 = *(const bf16x8*)&Plds[w][lo * 32 + ((16 + 4 * hi) ^ swzW)];

    __builtin_amdgcn_s_setprio(1);
#pragma unroll
    for (int n = 0; n < 4; ++n) {
      const int vr = n * 16 + lo;
      bf16x8 vfa = *(const bf16x8*)&VB[vr * 64 + ((hi ^ lo7) * 8)];
      bf16x8 vfb = *(const bf16x8*)&VB[vr * 64 + (((hi + 4) ^ lo7) * 8)];
      O[n] = __builtin_amdgcn_mfma_f32_16x16x32_bf16(vfa, pf0, O[n], 0, 0, 0);
      O[n] = __builtin_amdgcn_mfma_f32_16x16x32_bf16(vfb, pf1, O[n], 0, 0, 0);
    }
    __builtin_amdgcn_s_setprio(0);

    __syncthreads();
    cur ^= 1;
  }
#undef STAGE

  lr += __shfl_xor(lr, 16);
  lr += __shfl_xor(lr, 32);
  const float inv = 1.f / lr;

  const int h = bh & 15;
  const int token = q0 + lo;
  if (token < NN) {
    float* dst = AO + (size_t)(b * NN + token) * DIMM + h * 64 + hi * 4;
#pragma unroll
    for (int n = 0; n < 4; ++n) {
      f32x4 o = O[n];
      o[0] *= inv; o[1] *= inv; o[2] *= inv; o[3] *= inv;
      *(f32x4*)(dst + n * 16) = o;
    }
  }
}

// ---------------- LayerNorm over 1024, fp32 in, bf16 out ----------------
__global__ __launch_bounds__(256) void ln_kernel(
    const float* __restrict__ AO, const float* __restrict__ g,
    const float* __restrict__ be, __bf16* __restrict__ outb) {
  const int row = blockIdx.x;
  const int t = threadIdx.x;
  const float* x = AO + (size_t)row * DIMM;
  f32x4 v = ((const f32x4*)x)[t];
  float s = v[0] + v[1] + v[2] + v[3];
  float sq = v[0] * v[0] + v[1] * v[1] + v[2] * v[2] + v[3] * v[3];
#pragma unroll
  for (int m = 1; m < 64; m <<= 1) { s += __shfl_xor(s, m); sq += __shfl_xor(sq, m); }
  __shared__ float ss[4], ssq[4];
  int w = t >> 6, l = t & 63;
  if (l == 0) { ss[w] = s; ssq[w] = sq; }
  __syncthreads();
  s = ss[0] + ss[1] + ss[2] + ss[3];
  sq = ssq[0] + ssq[1] + ssq[2] + ssq[3];
  float mean = s * (1.f / 1024.f);
  float var = sq * (1.f / 1024.f) - mean * mean;
  float rstd = rsqrtf(var + 1e-5f);
  __bf16* o = outb + (size_t)row * DIMM + t * 4;
  const float* gp = g + t * 4;
  const float* bp2 = be + t * 4;
#pragma unroll
  for (int j = 0; j < 4; ++j) o[j] = (__bf16)((v[j] - mean) * rstd * gp[j] + bp2[j]);
}

// ---------------- launch ----------------
extern "C" void kernel_launch(void* const* d_in, const int* in_sizes, int n_in,
                              void* d_out, int out_size, void* d_ws, size_t ws_size,
                              hipStream_t stream) {
  const float* x   = (const float*)d_in[0];
  const float* val = (const float*)d_in[1];
  const void*  msk = d_in[2];
  const float* wq  = (const float*)d_in[3];
  const float* wk  = (const float*)d_in[4];
  const float* wv  = (const float*)d_in[5];
  const float* lng = (const float*)d_in[6];
  const float* lnb = (const float*)d_in[7];
  const float* wp  = (const float*)d_in[8];
  const float* bpv = (const float*)d_in[9];
  float* out = (float*)d_out;

  char* ws = (char*)d_ws;
  size_t off = 0;
  auto alloc = [&](size_t bytes) -> char* {
    char* p = ws + off;
    off += (bytes + 255) & ~(size_t)255;
    return p;
  };
  __bf16* xb   = (__bf16*)alloc((size_t)MPAD * 1024 * 2);  // also reused as LN output
  __bf16* vb   = (__bf16*)alloc((size_t)MPAD * 1536 * 2);
  __bf16* wqb  = (__bf16*)alloc((size_t)1024 * 1024 * 2);
  __bf16* wkvb = (__bf16*)alloc((size_t)2048 * 1536 * 2);  // wk ‖ wv
  __bf16* wpb  = (__bf16*)alloc((size_t)1024 * 1024 * 2);
  __bf16* Qb   = (__bf16*)alloc((size_t)64 * NPAD * 64 * 2);
  __bf16* Kb   = (__bf16*)alloc((size_t)64 * NPAD * 64 * 2);
  __bf16* Vtb  = (__bf16*)alloc((size_t)64 * 64 * NPAD * 2);
  float* AO    = (float*)alloc((size_t)MM * 1024 * 4);
  float* cosT  = (float*)alloc((size_t)NN * 64 * 4);
  float* sinT  = (float*)alloc((size_t)NN * 64 * 4);
  float* maskA = (float*)alloc((size_t)BB * NPAD * 4);

  // No memsets needed: pad A-rows feed MFMA with finite junk (results discarded
  // by mrow<MM guards); pad keys/rows in Qb/Kb/Vtb are finite junk killed by the
  // additive -1e30 mask (exp2 -> 0) or never read.

  cvt_inputs<<<2048, 256, 0, stream>>>(x, val, xb, vb);
  cvt_weights<<<1024, 256, 0, stream>>>(wq, wk, wv, wp, wqb, wkvb, wpb);
  rope_tables<<<(NN * 64 + 255) / 256, 256, 0, stream>>>(cosT, sinT);
  mask_prep<<<1, 256, 0, stream>>>(msk, maskA);

  // merged Q + KV projections: 2064 blocks
  gemm_qkv<<<dim3(2064), 256, 0, stream>>>(xb, wqb, vb, wkvb, Qb, Kb, Vtb, cosT, sinT);

  attn_kernel<<<dim3(64 * NT), 256, 0, stream>>>(Qb, Kb, Vtb, maskA, AO);

  ln_kernel<<<MM, 256, 0, stream>>>(AO, lng, lnb, xb);  // reuse xb as LN output

  // out-proj: 1376 blocks of 128 threads
  gemm_out<<<dim3(1376), 128, 0, stream>>>(xb, wpb, out, bpv);
}